// Round 1
// baseline (1127.959 us; speedup 1.0000x reference)
//
#include <hip/hip_runtime.h>

#define D 492
#define KC 40
#define DECAY 0.9f
#define EPS 1e-5f
#define PSPREAD 64   // dw partial copies

typedef __attribute__((ext_vector_type(8))) short bf16x8;
typedef __attribute__((ext_vector_type(4))) float f32x4;

// RNE fp32 -> bf16 (bit trick, no lib types)
__device__ __forceinline__ unsigned short f2bf(float f) {
  unsigned u = __float_as_uint(f);
  return (unsigned short)((u + 0x7fffu + ((u >> 16) & 1u)) >> 16);
}

// ---------------------------------------------------------------- K0: ||e_k||^2 + bf16 codebook
// Pre-converts the codebook to bf16, zero-padded to [48][512] so the assign
// kernel's B-fragments are single 16B loads with no bounds checks and no
// per-step conversion VALU.
__global__ void vq_prep(const float* __restrict__ emb, float* __restrict__ sq,
                        unsigned short* __restrict__ embb) {
  int k = blockIdx.x;      // 0..47
  int lane = threadIdx.x;  // 0..63
  int c0 = lane * 8;
  float s = 0.f;
  float v[8];
  #pragma unroll
  for (int j = 0; j < 8; j++) {
    int c = c0 + j;
    float f = (k < KC && c < D) ? emb[k * D + c] : 0.f;
    v[j] = f;
    s = fmaf(f, f, s);
  }
  bf16x8 u;
  #pragma unroll
  for (int j = 0; j < 8; j++) u[j] = (short)f2bf(v[j]);
  *(bf16x8*)&embb[k * 512 + c0] = u;
  #pragma unroll
  for (int off = 32; off; off >>= 1) s += __shfl_down(s, off, 64);
  if (k < KC && lane == 0) sq[k] = s;
}

// ---------------------------------------------------------------- K1: assign via bf16 MFMA
// Barrier-free, LDS-free main loop. 256 rows/block (grid 1024); wave w owns
// rows w*64..+63 (4 M-tiles x 3 N-tiles, 48 acc VGPRs). The A-fragment of
// mfma_f32_16x16x32_bf16 for lane l is rows (l&15), k = (l>>4)*8..+8 — a 32B
// contiguous slice of an x row — so each lane loads it straight from global
// (2x float4, 4 lanes/row -> 128B coalesced segments), converts RNE->bf16 in
// register, and feeds MFMA. B-fragments are 16B loads from the pre-converted
// padded bf16 codebook (49KB, L1-hot). No __syncthreads in the K loop: the
// compiler pipelines loads across steps; fused sumsq from the same registers.
// Epilogue: per-row argmin (C layout: col=lane&15, row=quad*4+reg), 16-lane
// xor-shuffle reduce; counts via LDS atomics.
__global__ __launch_bounds__(256, 2) void vq_assign(
    const float* __restrict__ x, const unsigned short* __restrict__ embb,
    const float* __restrict__ sq, int* __restrict__ idxp,
    float* __restrict__ counts, float* __restrict__ sumsq) {
  __shared__ float sq_s[KC];
  __shared__ float lcnt[KC];
  __shared__ float lss[4];
  int t = threadIdx.x;
  long row0 = (long)blockIdx.x * 256;
  if (t < KC) { sq_s[t] = sq[t]; lcnt[t] = 0.f; }

  int w = t >> 6, L = t & 63;
  int lm = L & 15, kq = L >> 4;

  const float* xr[4];
  #pragma unroll
  for (int m = 0; m < 4; m++)
    xr[m] = x + (row0 + w * 64 + m * 16 + lm) * (long)D + kq * 8;
  const unsigned short* bp = embb + lm * 512 + kq * 8;

  float ss = 0.f;
  f32x4 acc[4][3];
  #pragma unroll
  for (int m = 0; m < 4; m++)
    #pragma unroll
    for (int n = 0; n < 3; n++) acc[m][n] = (f32x4){0.f, 0.f, 0.f, 0.f};

  // ---- steps 0..14: all columns in-bounds, no predication
  #pragma unroll 2
  for (int step = 0; step < 15; step++) {
    int c = step * 32;
    float4 v0[4], v1[4];
    #pragma unroll
    for (int m = 0; m < 4; m++) {
      v0[m] = *(const float4*)(xr[m] + c);
      v1[m] = *(const float4*)(xr[m] + c + 4);
    }
    bf16x8 b[3];
    #pragma unroll
    for (int n = 0; n < 3; n++)
      b[n] = *(const bf16x8*)(bp + n * 16 * 512 + c);
    bf16x8 a[4];
    #pragma unroll
    for (int m = 0; m < 4; m++) {
      ss = fmaf(v0[m].x, v0[m].x, fmaf(v0[m].y, v0[m].y,
           fmaf(v0[m].z, v0[m].z, fmaf(v0[m].w, v0[m].w, ss))));
      ss = fmaf(v1[m].x, v1[m].x, fmaf(v1[m].y, v1[m].y,
           fmaf(v1[m].z, v1[m].z, fmaf(v1[m].w, v1[m].w, ss))));
      a[m][0] = (short)f2bf(v0[m].x); a[m][1] = (short)f2bf(v0[m].y);
      a[m][2] = (short)f2bf(v0[m].z); a[m][3] = (short)f2bf(v0[m].w);
      a[m][4] = (short)f2bf(v1[m].x); a[m][5] = (short)f2bf(v1[m].y);
      a[m][6] = (short)f2bf(v1[m].z); a[m][7] = (short)f2bf(v1[m].w);
    }
    #pragma unroll
    for (int m = 0; m < 4; m++)
      #pragma unroll
      for (int n = 0; n < 3; n++)
        acc[m][n] = __builtin_amdgcn_mfma_f32_16x16x32_bf16(a[m], b[n], acc[m][n], 0, 0, 0);
  }

  // ---- tail step 15: cols 480..511, predicate per float4 (D=492, 4-aligned)
  {
    int c = 480;
    int cl = c + kq * 8;  // lane's first column: 480/488/496/504
    float4 z = make_float4(0.f, 0.f, 0.f, 0.f);
    float4 v0[4], v1[4];
    #pragma unroll
    for (int m = 0; m < 4; m++) {
      v0[m] = (cl < D) ? *(const float4*)(xr[m] + c) : z;
      v1[m] = (cl + 4 < D) ? *(const float4*)(xr[m] + c + 4) : z;
    }
    bf16x8 b[3];
    #pragma unroll
    for (int n = 0; n < 3; n++)
      b[n] = *(const bf16x8*)(bp + n * 16 * 512 + c);
    bf16x8 a[4];
    #pragma unroll
    for (int m = 0; m < 4; m++) {
      ss = fmaf(v0[m].x, v0[m].x, fmaf(v0[m].y, v0[m].y,
           fmaf(v0[m].z, v0[m].z, fmaf(v0[m].w, v0[m].w, ss))));
      ss = fmaf(v1[m].x, v1[m].x, fmaf(v1[m].y, v1[m].y,
           fmaf(v1[m].z, v1[m].z, fmaf(v1[m].w, v1[m].w, ss))));
      a[m][0] = (short)f2bf(v0[m].x); a[m][1] = (short)f2bf(v0[m].y);
      a[m][2] = (short)f2bf(v0[m].z); a[m][3] = (short)f2bf(v0[m].w);
      a[m][4] = (short)f2bf(v1[m].x); a[m][5] = (short)f2bf(v1[m].y);
      a[m][6] = (short)f2bf(v1[m].z); a[m][7] = (short)f2bf(v1[m].w);
    }
    #pragma unroll
    for (int m = 0; m < 4; m++)
      #pragma unroll
      for (int n = 0; n < 3; n++)
        acc[m][n] = __builtin_amdgcn_mfma_f32_16x16x32_bf16(a[m], b[n], acc[m][n], 0, 0, 0);
  }

  __syncthreads();  // lcnt zeroed + sq_s visible before epilogue

  // ---- epilogue: per-row argmin of sq[k] - 2*dot (||x||^2 dropped)
  #pragma unroll
  for (int m = 0; m < 4; m++) {
    #pragma unroll
    for (int reg = 0; reg < 4; reg++) {
      float best = 3.4e38f; int bi = 0;
      #pragma unroll
      for (int n = 0; n < 3; n++) {
        int col = n * 16 + lm;
        if (col < KC) {
          float v = sq_s[col] - 2.f * acc[m][n][reg];
          if (v < best || (v == best && col < bi)) { best = v; bi = col; }
        }
      }
      #pragma unroll
      for (int off = 1; off < 16; off <<= 1) {
        float ov = __shfl_xor(best, off, 64);
        int oi = __shfl_xor(bi, off, 64);
        if (ov < best || (ov == best && oi < bi)) { best = ov; bi = oi; }
      }
      if (lm == 0) {
        int r = w * 64 + m * 16 + kq * 4 + reg;
        idxp[row0 + r] = bi;
        atomicAdd(&lcnt[bi], 1.f);
      }
    }
  }
  // ---- sumsq + counts flush
  #pragma unroll
  for (int off = 32; off; off >>= 1) ss += __shfl_down(ss, off, 64);
  if (L == 0) lss[w] = ss;
  __syncthreads();
  if (t == 0) atomicAdd(sumsq, lss[0] + lss[1] + lss[2] + lss[3]);
  if (t < KC) atomicAdd(&counts[t], lcnt[t]);
}

// ---------------------------------------------------------------- K2: dw segment-sum
// 512 rows/block (grid 512), 128 threads; thread t owns cols 4t..4t+3
// (t<123). Counting-sort rows by code into packed order[] (r | k<<9), then
// stream ALL rows as one flat list: 8-row prefetch double-buffer, register
// float4 accumulator, wave-uniform flush-on-k-change (one atomic burst per
// k-group) into 1 of 64 spread partial copies.
__global__ __launch_bounds__(128) void vq_dw(
    const float* __restrict__ x, const int* __restrict__ idxp,
    float* __restrict__ dwp) {
  __shared__ int cnt[KC], base[KC], pos[KC];
  __shared__ unsigned short order[512];
  int t = threadIdx.x;
  long row0 = (long)blockIdx.x * 512;
  if (t < KC) cnt[t] = 0;
  __syncthreads();
  int myk[4];
  #pragma unroll
  for (int u = 0; u < 4; u++) {
    myk[u] = idxp[row0 + t + u * 128];
    atomicAdd(&cnt[myk[u]], 1);
  }
  __syncthreads();
  if (t == 0) {
    int s = 0;
    for (int k = 0; k < KC; k++) { base[k] = s; pos[k] = s; s += cnt[k]; }
  }
  __syncthreads();
  #pragma unroll
  for (int u = 0; u < 4; u++) {
    int p = atomicAdd(&pos[myk[u]], 1);
    order[p] = (unsigned short)((t + u * 128) | (myk[u] << 9));
  }
  __syncthreads();

  int c = 4 * t;
  bool act = c < D;  // 123 of 128 threads carry columns
  float* dst = dwp + (long)(blockIdx.x & (PSPREAD - 1)) * (KC * D);
  float4 a = make_float4(0.f, 0.f, 0.f, 0.f);
  int kcur = -1;

  int pk[8], pk2[8];
  float4 v[8], v2[8];
  #pragma unroll
  for (int u = 0; u < 8; u++) pk[u] = order[u];
  #pragma unroll
  for (int u = 0; u < 8; u++)
    v[u] = act ? *(const float4*)&x[(row0 + (pk[u] & 511)) * D + c]
               : make_float4(0.f, 0.f, 0.f, 0.f);

  for (int j0 = 0; j0 < 512; j0 += 8) {
    if (j0 + 8 < 512) {
      #pragma unroll
      for (int u = 0; u < 8; u++) pk2[u] = order[j0 + 8 + u];
      #pragma unroll
      for (int u = 0; u < 8; u++)
        v2[u] = act ? *(const float4*)&x[(row0 + (pk2[u] & 511)) * D + c]
                    : make_float4(0.f, 0.f, 0.f, 0.f);
    }
    #pragma unroll
    for (int u = 0; u < 8; u++) {
      int k = pk[u] >> 9;           // wave-uniform
      if (k != kcur) {              // uniform branch, ~40 flushes per block
        if (kcur >= 0 && act) {
          atomicAdd(&dst[kcur * D + c], a.x);
          atomicAdd(&dst[kcur * D + c + 1], a.y);
          atomicAdd(&dst[kcur * D + c + 2], a.z);
          atomicAdd(&dst[kcur * D + c + 3], a.w);
        }
        a = v[u]; kcur = k;
      } else {
        a.x += v[u].x; a.y += v[u].y; a.z += v[u].z; a.w += v[u].w;
      }
    }
    #pragma unroll
    for (int u = 0; u < 8; u++) { pk[u] = pk2[u]; v[u] = v2[u]; }
  }
  if (kcur >= 0 && act) {
    atomicAdd(&dst[kcur * D + c], a.x);
    atomicAdd(&dst[kcur * D + c + 1], a.y);
    atomicAdd(&dst[kcur * D + c + 2], a.z);
    atomicAdd(&dst[kcur * D + c + 3], a.w);
  }
}

// ---------------------------------------------------------------- K3a: reduce 64 partials -> dw
__global__ __launch_bounds__(256) void vq_reduce(
    const float* __restrict__ dwp, float* __restrict__ dw) {
  int i = blockIdx.x * 256 + threadIdx.x;
  if (i >= KC * D) return;
  float s = 0.f;
  #pragma unroll 8
  for (int cpy = 0; cpy < PSPREAD; cpy++) s += dwp[cpy * (KC * D) + i];
  dw[i] = s;
}

// ---------------------------------------------------------------- K3b: EMA + closed-form loss
// loss*N*D = sumsq - 2*sum_k E_k.dw_k + sum_k counts_k*||E_k||^2
__global__ __launch_bounds__(256) void vq_final(
    const float* __restrict__ ema_w, const float* __restrict__ ema_cs,
    const float* __restrict__ counts, const float* __restrict__ dw,
    const float* __restrict__ sumsq, float* __restrict__ out, long NDl) {
  __shared__ float lcs[KC], lcnt[KC];
  __shared__ float r1[4], r2[4];
  int t = threadIdx.x;
  if (t < KC) {
    float c = counts[t];
    lcnt[t] = c;
    lcs[t] = ema_cs[t] * DECAY + (1.f - DECAY) * c;
  }
  __syncthreads();
  if (t == 0) {
    float n = 0.f;
    for (int k = 0; k < KC; k++) n += lcs[k];
    for (int k = 0; k < KC; k++) lcs[k] = (lcs[k] + EPS) / (n + KC * EPS) * n;
  }
  __syncthreads();
  float t1 = 0.f, t2 = 0.f;
  for (int i = t; i < KC * D; i += 256) {
    float dwv = dw[i];
    int k = i / D;
    float E = (DECAY * ema_w[i] + (1.f - DECAY) * dwv) / lcs[k];
    t1 = fmaf(lcnt[k] * E, E, t1);
    t2 = fmaf(E, dwv, t2);
  }
  #pragma unroll
  for (int off = 32; off; off >>= 1) {
    t1 += __shfl_down(t1, off, 64);
    t2 += __shfl_down(t2, off, 64);
  }
  int lane = t & 63, w = t >> 6;
  if (lane == 0) { r1[w] = t1; r2[w] = t2; }
  __syncthreads();
  if (t == 0) {
    double T1 = (double)r1[0] + r1[1] + r1[2] + r1[3];
    double T2 = (double)r2[0] + r2[1] + r2[2] + r2[3];
    double L = ((double)sumsq[0] - 2.0 * T2 + T1) / (double)NDl;
    out[0] = (float)L;
  }
}

// ---------------------------------------------------------------- launch
extern "C" void kernel_launch(void* const* d_in, const int* in_sizes, int n_in,
                              void* d_out, int out_size, void* d_ws, size_t ws_size,
                              hipStream_t stream) {
  const float* x = (const float*)d_in[0];
  const float* emb = (const float*)d_in[1];
  const float* ema_w = (const float*)d_in[2];
  const float* ema_cs = (const float*)d_in[3];
  float* out = (float*)d_out;
  long NDl = (long)in_sizes[0];
  int N = (int)(NDl / D);  // 262144

  char* ws = (char*)d_ws;
  float* sq = (float*)ws;                         // 40 f
  float* counts = (float*)(ws + 256);             // 40 f
  float* sumsq = (float*)(ws + 512);              // 1 f
  float* dw = (float*)(ws + 1024);                // KC*D f (reduced)
  size_t part_off = 1024 + (size_t)KC * D * 4;
  part_off = (part_off + 255) & ~(size_t)255;
  float* dwp = (float*)(ws + part_off);           // PSPREAD * KC*D f
  size_t idx_off = part_off + (size_t)PSPREAD * KC * D * 4;
  int* idxp = (int*)(ws + idx_off);               // N ints
  size_t embb_off = idx_off + (size_t)N * 4;
  unsigned short* embb = (unsigned short*)(ws + embb_off);  // 48*512 bf16

  hipMemsetAsync(ws + 256, 0, 768, stream);
  hipMemsetAsync(ws + part_off, 0, (size_t)PSPREAD * KC * D * 4, stream);

  vq_prep<<<48, 64, 0, stream>>>(emb, sq, embb);
  vq_assign<<<N / 256, 256, 0, stream>>>(x, embb, sq, idxp, counts, sumsq);
  vq_dw<<<N / 512, 128, 0, stream>>>(x, idxp, dwp);
  vq_reduce<<<(KC * D + 255) / 256, 256, 0, stream>>>(dwp, dw);
  vq_final<<<1, 256, 0, stream>>>(ema_w, ema_cs, counts, dw, sumsq, out, NDl);
}

// Round 2
// 932.337 us; speedup vs baseline: 1.2098x; 1.2098x over previous
//
#include <hip/hip_runtime.h>

#define D 492
#define KC 40
#define DECAY 0.9f
#define EPS 1e-5f
#define PSPREAD 64   // dw partial copies

typedef __attribute__((ext_vector_type(8))) short bf16x8;
typedef __attribute__((ext_vector_type(4))) float f32x4;

// RNE fp32 -> bf16 (bit trick, no lib types)
__device__ __forceinline__ unsigned short f2bf(float f) {
  unsigned u = __float_as_uint(f);
  return (unsigned short)((u + 0x7fffu + ((u >> 16) & 1u)) >> 16);
}

// ---------------------------------------------------------------- K0: ||e_k||^2 + bf16 codebook
// Pre-converts the codebook to bf16, zero-padded to [48][512] so the assign
// kernel's B-fragments are single 16B loads with no bounds checks and no
// per-step conversion VALU.
__global__ void vq_prep(const float* __restrict__ emb, float* __restrict__ sq,
                        unsigned short* __restrict__ embb) {
  int k = blockIdx.x;      // 0..47
  int lane = threadIdx.x;  // 0..63
  int c0 = lane * 8;
  float s = 0.f;
  float v[8];
  #pragma unroll
  for (int j = 0; j < 8; j++) {
    int c = c0 + j;
    float f = (k < KC && c < D) ? emb[k * D + c] : 0.f;
    v[j] = f;
    s = fmaf(f, f, s);
  }
  bf16x8 u;
  #pragma unroll
  for (int j = 0; j < 8; j++) u[j] = (short)f2bf(v[j]);
  *(bf16x8*)&embb[k * 512 + c0] = u;
  #pragma unroll
  for (int off = 32; off; off >>= 1) s += __shfl_down(s, off, 64);
  if (k < KC && lane == 0) sq[k] = s;
}

// ---------------------------------------------------------------- K1: assign via bf16 MFMA
// Barrier-free, LDS-free main loop; direct global->register A-fragments.
// 256 rows/block (grid 1024); wave w owns rows w*64..+63 (4 M x 3 N tiles,
// 48 acc VGPRs). A-fragment of mfma_f32_16x16x32_bf16 for lane l is row
// (l&15), k=(l>>4)*8..+8 — a 32B contiguous row slice — loaded as 2x float4
// straight from global, converted RNE->bf16 in register. B-fragments are
// 16B loads from the padded bf16 codebook (49KB, L1/L2-hot).
// REGISTER-PRESSURE DISCIPLINE (round-1 post-mortem: unroll-2 spilled ~60
// float4 temporaries -> 375MB scratch writes): K-loop pinned to unroll 1,
// each step split into two m-groups (m=0,1 then m=2,3) so peak live
// temporaries ~28 regs; __launch_bounds__(256,4) caps at 128 VGPR with
// 4 blocks/CU (16 waves/CU TLP hides load latency; no barriers to stall).
__global__ __launch_bounds__(256, 4) void vq_assign(
    const float* __restrict__ x, const unsigned short* __restrict__ embb,
    const float* __restrict__ sq, int* __restrict__ idxp,
    float* __restrict__ counts, float* __restrict__ sumsq) {
  __shared__ float sq_s[KC];
  __shared__ float lcnt[KC];
  __shared__ float lss[4];
  int t = threadIdx.x;
  long row0 = (long)blockIdx.x * 256;
  if (t < KC) { sq_s[t] = sq[t]; lcnt[t] = 0.f; }

  int w = t >> 6, L = t & 63;
  int lm = L & 15, kq = L >> 4;

  const float* xr0 = x + (row0 + w * 64 + 0 * 16 + lm) * (long)D + kq * 8;
  const float* xr1 = x + (row0 + w * 64 + 1 * 16 + lm) * (long)D + kq * 8;
  const float* xr2 = x + (row0 + w * 64 + 2 * 16 + lm) * (long)D + kq * 8;
  const float* xr3 = x + (row0 + w * 64 + 3 * 16 + lm) * (long)D + kq * 8;
  const unsigned short* bp = embb + lm * 512 + kq * 8;

  float ss = 0.f;
  f32x4 acc[4][3];
  #pragma unroll
  for (int m = 0; m < 4; m++)
    #pragma unroll
    for (int n = 0; n < 3; n++) acc[m][n] = (f32x4){0.f, 0.f, 0.f, 0.f};

  // ---- steps 0..14: all columns in-bounds, no predication
  #pragma unroll 1
  for (int step = 0; step < 15; step++) {
    int c = step * 32;
    bf16x8 b0 = *(const bf16x8*)(bp + 0 * 16 * 512 + c);
    bf16x8 b1 = *(const bf16x8*)(bp + 1 * 16 * 512 + c);
    bf16x8 b2 = *(const bf16x8*)(bp + 2 * 16 * 512 + c);
    // group A: m = 0,1
    {
      float4 p0 = *(const float4*)(xr0 + c);
      float4 p1 = *(const float4*)(xr0 + c + 4);
      float4 q0 = *(const float4*)(xr1 + c);
      float4 q1 = *(const float4*)(xr1 + c + 4);
      ss = fmaf(p0.x, p0.x, fmaf(p0.y, p0.y, fmaf(p0.z, p0.z, fmaf(p0.w, p0.w, ss))));
      ss = fmaf(p1.x, p1.x, fmaf(p1.y, p1.y, fmaf(p1.z, p1.z, fmaf(p1.w, p1.w, ss))));
      ss = fmaf(q0.x, q0.x, fmaf(q0.y, q0.y, fmaf(q0.z, q0.z, fmaf(q0.w, q0.w, ss))));
      ss = fmaf(q1.x, q1.x, fmaf(q1.y, q1.y, fmaf(q1.z, q1.z, fmaf(q1.w, q1.w, ss))));
      bf16x8 a0, a1;
      a0[0] = (short)f2bf(p0.x); a0[1] = (short)f2bf(p0.y);
      a0[2] = (short)f2bf(p0.z); a0[3] = (short)f2bf(p0.w);
      a0[4] = (short)f2bf(p1.x); a0[5] = (short)f2bf(p1.y);
      a0[6] = (short)f2bf(p1.z); a0[7] = (short)f2bf(p1.w);
      a1[0] = (short)f2bf(q0.x); a1[1] = (short)f2bf(q0.y);
      a1[2] = (short)f2bf(q0.z); a1[3] = (short)f2bf(q0.w);
      a1[4] = (short)f2bf(q1.x); a1[5] = (short)f2bf(q1.y);
      a1[6] = (short)f2bf(q1.z); a1[7] = (short)f2bf(q1.w);
      acc[0][0] = __builtin_amdgcn_mfma_f32_16x16x32_bf16(a0, b0, acc[0][0], 0, 0, 0);
      acc[0][1] = __builtin_amdgcn_mfma_f32_16x16x32_bf16(a0, b1, acc[0][1], 0, 0, 0);
      acc[0][2] = __builtin_amdgcn_mfma_f32_16x16x32_bf16(a0, b2, acc[0][2], 0, 0, 0);
      acc[1][0] = __builtin_amdgcn_mfma_f32_16x16x32_bf16(a1, b0, acc[1][0], 0, 0, 0);
      acc[1][1] = __builtin_amdgcn_mfma_f32_16x16x32_bf16(a1, b1, acc[1][1], 0, 0, 0);
      acc[1][2] = __builtin_amdgcn_mfma_f32_16x16x32_bf16(a1, b2, acc[1][2], 0, 0, 0);
    }
    // group B: m = 2,3
    {
      float4 p0 = *(const float4*)(xr2 + c);
      float4 p1 = *(const float4*)(xr2 + c + 4);
      float4 q0 = *(const float4*)(xr3 + c);
      float4 q1 = *(const float4*)(xr3 + c + 4);
      ss = fmaf(p0.x, p0.x, fmaf(p0.y, p0.y, fmaf(p0.z, p0.z, fmaf(p0.w, p0.w, ss))));
      ss = fmaf(p1.x, p1.x, fmaf(p1.y, p1.y, fmaf(p1.z, p1.z, fmaf(p1.w, p1.w, ss))));
      ss = fmaf(q0.x, q0.x, fmaf(q0.y, q0.y, fmaf(q0.z, q0.z, fmaf(q0.w, q0.w, ss))));
      ss = fmaf(q1.x, q1.x, fmaf(q1.y, q1.y, fmaf(q1.z, q1.z, fmaf(q1.w, q1.w, ss))));
      bf16x8 a2, a3;
      a2[0] = (short)f2bf(p0.x); a2[1] = (short)f2bf(p0.y);
      a2[2] = (short)f2bf(p0.z); a2[3] = (short)f2bf(p0.w);
      a2[4] = (short)f2bf(p1.x); a2[5] = (short)f2bf(p1.y);
      a2[6] = (short)f2bf(p1.z); a2[7] = (short)f2bf(p1.w);
      a3[0] = (short)f2bf(q0.x); a3[1] = (short)f2bf(q0.y);
      a3[2] = (short)f2bf(q0.z); a3[3] = (short)f2bf(q0.w);
      a3[4] = (short)f2bf(q1.x); a3[5] = (short)f2bf(q1.y);
      a3[6] = (short)f2bf(q1.z); a3[7] = (short)f2bf(q1.w);
      acc[2][0] = __builtin_amdgcn_mfma_f32_16x16x32_bf16(a2, b0, acc[2][0], 0, 0, 0);
      acc[2][1] = __builtin_amdgcn_mfma_f32_16x16x32_bf16(a2, b1, acc[2][1], 0, 0, 0);
      acc[2][2] = __builtin_amdgcn_mfma_f32_16x16x32_bf16(a2, b2, acc[2][2], 0, 0, 0);
      acc[3][0] = __builtin_amdgcn_mfma_f32_16x16x32_bf16(a3, b0, acc[3][0], 0, 0, 0);
      acc[3][1] = __builtin_amdgcn_mfma_f32_16x16x32_bf16(a3, b1, acc[3][1], 0, 0, 0);
      acc[3][2] = __builtin_amdgcn_mfma_f32_16x16x32_bf16(a3, b2, acc[3][2], 0, 0, 0);
    }
  }

  // ---- tail step 15: cols 480..511, predicate per float4 (D=492, 4-aligned)
  {
    int c = 480;
    int cl = c + kq * 8;  // lane's first column: 480/488/496/504
    bool in0 = cl < D, in1 = cl + 4 < D;
    float4 z = make_float4(0.f, 0.f, 0.f, 0.f);
    bf16x8 b0 = *(const bf16x8*)(bp + 0 * 16 * 512 + c);
    bf16x8 b1 = *(const bf16x8*)(bp + 1 * 16 * 512 + c);
    bf16x8 b2 = *(const bf16x8*)(bp + 2 * 16 * 512 + c);
    const float* xrs[4] = { xr0, xr1, xr2, xr3 };
    #pragma unroll
    for (int m = 0; m < 4; m++) {
      float4 p0 = in0 ? *(const float4*)(xrs[m] + c) : z;
      float4 p1 = in1 ? *(const float4*)(xrs[m] + c + 4) : z;
      ss = fmaf(p0.x, p0.x, fmaf(p0.y, p0.y, fmaf(p0.z, p0.z, fmaf(p0.w, p0.w, ss))));
      ss = fmaf(p1.x, p1.x, fmaf(p1.y, p1.y, fmaf(p1.z, p1.z, fmaf(p1.w, p1.w, ss))));
      bf16x8 a;
      a[0] = (short)f2bf(p0.x); a[1] = (short)f2bf(p0.y);
      a[2] = (short)f2bf(p0.z); a[3] = (short)f2bf(p0.w);
      a[4] = (short)f2bf(p1.x); a[5] = (short)f2bf(p1.y);
      a[6] = (short)f2bf(p1.z); a[7] = (short)f2bf(p1.w);
      acc[m][0] = __builtin_amdgcn_mfma_f32_16x16x32_bf16(a, b0, acc[m][0], 0, 0, 0);
      acc[m][1] = __builtin_amdgcn_mfma_f32_16x16x32_bf16(a, b1, acc[m][1], 0, 0, 0);
      acc[m][2] = __builtin_amdgcn_mfma_f32_16x16x32_bf16(a, b2, acc[m][2], 0, 0, 0);
    }
  }

  __syncthreads();  // lcnt zeroed + sq_s visible before epilogue

  // ---- epilogue: per-row argmin of sq[k] - 2*dot (||x||^2 dropped)
  #pragma unroll
  for (int m = 0; m < 4; m++) {
    #pragma unroll
    for (int reg = 0; reg < 4; reg++) {
      float best = 3.4e38f; int bi = 0;
      #pragma unroll
      for (int n = 0; n < 3; n++) {
        int col = n * 16 + lm;
        if (col < KC) {
          float v = sq_s[col] - 2.f * acc[m][n][reg];
          if (v < best || (v == best && col < bi)) { best = v; bi = col; }
        }
      }
      #pragma unroll
      for (int off = 1; off < 16; off <<= 1) {
        float ov = __shfl_xor(best, off, 64);
        int oi = __shfl_xor(bi, off, 64);
        if (ov < best || (ov == best && oi < bi)) { best = ov; bi = oi; }
      }
      if (lm == 0) {
        int r = w * 64 + m * 16 + kq * 4 + reg;
        idxp[row0 + r] = bi;
        atomicAdd(&lcnt[bi], 1.f);
      }
    }
  }
  // ---- sumsq + counts flush
  #pragma unroll
  for (int off = 32; off; off >>= 1) ss += __shfl_down(ss, off, 64);
  if (L == 0) lss[w] = ss;
  __syncthreads();
  if (t == 0) atomicAdd(sumsq, lss[0] + lss[1] + lss[2] + lss[3]);
  if (t < KC) atomicAdd(&counts[t], lcnt[t]);
}

// ---------------------------------------------------------------- K2: dw segment-sum
// 512 rows/block (grid 512), 128 threads; thread t owns cols 4t..4t+3
// (t<123). Counting-sort rows by code into packed order[] (r | k<<9), then
// stream ALL rows as one flat list: 8-row prefetch double-buffer, register
// float4 accumulator, wave-uniform flush-on-k-change (one atomic burst per
// k-group) into 1 of 64 spread partial copies.
__global__ __launch_bounds__(128) void vq_dw(
    const float* __restrict__ x, const int* __restrict__ idxp,
    float* __restrict__ dwp) {
  __shared__ int cnt[KC], base[KC], pos[KC];
  __shared__ unsigned short order[512];
  int t = threadIdx.x;
  long row0 = (long)blockIdx.x * 512;
  if (t < KC) cnt[t] = 0;
  __syncthreads();
  int myk[4];
  #pragma unroll
  for (int u = 0; u < 4; u++) {
    myk[u] = idxp[row0 + t + u * 128];
    atomicAdd(&cnt[myk[u]], 1);
  }
  __syncthreads();
  if (t == 0) {
    int s = 0;
    for (int k = 0; k < KC; k++) { base[k] = s; pos[k] = s; s += cnt[k]; }
  }
  __syncthreads();
  #pragma unroll
  for (int u = 0; u < 4; u++) {
    int p = atomicAdd(&pos[myk[u]], 1);
    order[p] = (unsigned short)((t + u * 128) | (myk[u] << 9));
  }
  __syncthreads();

  int c = 4 * t;
  bool act = c < D;  // 123 of 128 threads carry columns
  float* dst = dwp + (long)(blockIdx.x & (PSPREAD - 1)) * (KC * D);
  float4 a = make_float4(0.f, 0.f, 0.f, 0.f);
  int kcur = -1;

  int pk[8], pk2[8];
  float4 v[8], v2[8];
  #pragma unroll
  for (int u = 0; u < 8; u++) pk[u] = order[u];
  #pragma unroll
  for (int u = 0; u < 8; u++)
    v[u] = act ? *(const float4*)&x[(row0 + (pk[u] & 511)) * D + c]
               : make_float4(0.f, 0.f, 0.f, 0.f);

  for (int j0 = 0; j0 < 512; j0 += 8) {
    if (j0 + 8 < 512) {
      #pragma unroll
      for (int u = 0; u < 8; u++) pk2[u] = order[j0 + 8 + u];
      #pragma unroll
      for (int u = 0; u < 8; u++)
        v2[u] = act ? *(const float4*)&x[(row0 + (pk2[u] & 511)) * D + c]
                    : make_float4(0.f, 0.f, 0.f, 0.f);
    }
    #pragma unroll
    for (int u = 0; u < 8; u++) {
      int k = pk[u] >> 9;           // wave-uniform
      if (k != kcur) {              // uniform branch, ~40 flushes per block
        if (kcur >= 0 && act) {
          atomicAdd(&dst[kcur * D + c], a.x);
          atomicAdd(&dst[kcur * D + c + 1], a.y);
          atomicAdd(&dst[kcur * D + c + 2], a.z);
          atomicAdd(&dst[kcur * D + c + 3], a.w);
        }
        a = v[u]; kcur = k;
      } else {
        a.x += v[u].x; a.y += v[u].y; a.z += v[u].z; a.w += v[u].w;
      }
    }
    #pragma unroll
    for (int u = 0; u < 8; u++) { pk[u] = pk2[u]; v[u] = v2[u]; }
  }
  if (kcur >= 0 && act) {
    atomicAdd(&dst[kcur * D + c], a.x);
    atomicAdd(&dst[kcur * D + c + 1], a.y);
    atomicAdd(&dst[kcur * D + c + 2], a.z);
    atomicAdd(&dst[kcur * D + c + 3], a.w);
  }
}

// ---------------------------------------------------------------- K3a: reduce 64 partials -> dw
__global__ __launch_bounds__(256) void vq_reduce(
    const float* __restrict__ dwp, float* __restrict__ dw) {
  int i = blockIdx.x * 256 + threadIdx.x;
  if (i >= KC * D) return;
  float s = 0.f;
  #pragma unroll 8
  for (int cpy = 0; cpy < PSPREAD; cpy++) s += dwp[cpy * (KC * D) + i];
  dw[i] = s;
}

// ---------------------------------------------------------------- K3b: EMA + closed-form loss
// loss*N*D = sumsq - 2*sum_k E_k.dw_k + sum_k counts_k*||E_k||^2
__global__ __launch_bounds__(256) void vq_final(
    const float* __restrict__ ema_w, const float* __restrict__ ema_cs,
    const float* __restrict__ counts, const float* __restrict__ dw,
    const float* __restrict__ sumsq, float* __restrict__ out, long NDl) {
  __shared__ float lcs[KC], lcnt[KC];
  __shared__ float r1[4], r2[4];
  int t = threadIdx.x;
  if (t < KC) {
    float c = counts[t];
    lcnt[t] = c;
    lcs[t] = ema_cs[t] * DECAY + (1.f - DECAY) * c;
  }
  __syncthreads();
  if (t == 0) {
    float n = 0.f;
    for (int k = 0; k < KC; k++) n += lcs[k];
    for (int k = 0; k < KC; k++) lcs[k] = (lcs[k] + EPS) / (n + KC * EPS) * n;
  }
  __syncthreads();
  float t1 = 0.f, t2 = 0.f;
  for (int i = t; i < KC * D; i += 256) {
    float dwv = dw[i];
    int k = i / D;
    float E = (DECAY * ema_w[i] + (1.f - DECAY) * dwv) / lcs[k];
    t1 = fmaf(lcnt[k] * E, E, t1);
    t2 = fmaf(E, dwv, t2);
  }
  #pragma unroll
  for (int off = 32; off; off >>= 1) {
    t1 += __shfl_down(t1, off, 64);
    t2 += __shfl_down(t2, off, 64);
  }
  int lane = t & 63, w = t >> 6;
  if (lane == 0) { r1[w] = t1; r2[w] = t2; }
  __syncthreads();
  if (t == 0) {
    double T1 = (double)r1[0] + r1[1] + r1[2] + r1[3];
    double T2 = (double)r2[0] + r2[1] + r2[2] + r2[3];
    double L = ((double)sumsq[0] - 2.0 * T2 + T1) / (double)NDl;
    out[0] = (float)L;
  }
}

// ---------------------------------------------------------------- launch
extern "C" void kernel_launch(void* const* d_in, const int* in_sizes, int n_in,
                              void* d_out, int out_size, void* d_ws, size_t ws_size,
                              hipStream_t stream) {
  const float* x = (const float*)d_in[0];
  const float* emb = (const float*)d_in[1];
  const float* ema_w = (const float*)d_in[2];
  const float* ema_cs = (const float*)d_in[3];
  float* out = (float*)d_out;
  long NDl = (long)in_sizes[0];
  int N = (int)(NDl / D);  // 262144

  char* ws = (char*)d_ws;
  float* sq = (float*)ws;                         // 40 f
  float* counts = (float*)(ws + 256);             // 40 f
  float* sumsq = (float*)(ws + 512);              // 1 f
  float* dw = (float*)(ws + 1024);                // KC*D f (reduced)
  size_t part_off = 1024 + (size_t)KC * D * 4;
  part_off = (part_off + 255) & ~(size_t)255;
  float* dwp = (float*)(ws + part_off);           // PSPREAD * KC*D f
  size_t idx_off = part_off + (size_t)PSPREAD * KC * D * 4;
  int* idxp = (int*)(ws + idx_off);               // N ints
  size_t embb_off = idx_off + (size_t)N * 4;
  unsigned short* embb = (unsigned short*)(ws + embb_off);  // 48*512 bf16

  hipMemsetAsync(ws + 256, 0, 768, stream);
  hipMemsetAsync(ws + part_off, 0, (size_t)PSPREAD * KC * D * 4, stream);

  vq_prep<<<48, 64, 0, stream>>>(emb, sq, embb);
  vq_assign<<<N / 256, 256, 0, stream>>>(x, embb, sq, idxp, counts, sumsq);
  vq_dw<<<N / 512, 128, 0, stream>>>(x, idxp, dwp);
  vq_reduce<<<(KC * D + 255) / 256, 256, 0, stream>>>(dwp, dw);
  vq_final<<<1, 256, 0, stream>>>(ema_w, ema_cs, counts, dw, sumsq, out, NDl);
}

// Round 3
// 898.169 us; speedup vs baseline: 1.2558x; 1.0380x over previous
//
#include <hip/hip_runtime.h>

#define D 492
#define KC 40
#define DECAY 0.9f
#define EPS 1e-5f
#define PSPREAD 64   // dw partial copies

typedef __attribute__((ext_vector_type(8))) short bf16x8;
typedef __attribute__((ext_vector_type(4))) float f32x4;

// RNE fp32 -> bf16 (bit trick, no lib types)
__device__ __forceinline__ unsigned short f2bf(float f) {
  unsigned u = __float_as_uint(f);
  return (unsigned short)((u + 0x7fffu + ((u >> 16) & 1u)) >> 16);
}

// ---------------------------------------------------------------- K0: ||e_k||^2 + bf16 codebook
// Pre-converts the codebook to bf16, zero-padded to [48][512] so the assign
// kernel's B-fragments are single 16B loads with no bounds checks and no
// per-step conversion VALU.
__global__ void vq_prep(const float* __restrict__ emb, float* __restrict__ sq,
                        unsigned short* __restrict__ embb) {
  int k = blockIdx.x;      // 0..47
  int lane = threadIdx.x;  // 0..63
  int c0 = lane * 8;
  float s = 0.f;
  float v[8];
  #pragma unroll
  for (int j = 0; j < 8; j++) {
    int c = c0 + j;
    float f = (k < KC && c < D) ? emb[k * D + c] : 0.f;
    v[j] = f;
    s = fmaf(f, f, s);
  }
  bf16x8 u;
  #pragma unroll
  for (int j = 0; j < 8; j++) u[j] = (short)f2bf(v[j]);
  *(bf16x8*)&embb[k * 512 + c0] = u;
  #pragma unroll
  for (int off = 32; off; off >>= 1) s += __shfl_down(s, off, 64);
  if (k < KC && lane == 0) sq[k] = s;
}

// ---------------------------------------------------------------- K1: assign via bf16 MFMA
// Round-3: explicit register double-buffer pipeline. Wave owns 32 rows
// (2 M-tiles x 3 N-tiles, acc=24 VGPR), block = 128 rows, grid = 2048.
// LOADX issues step s+1's 4 float4 x-loads into the idle buffer BEFORE
// COMPUTE consumes step s's buffer, so the vmcnt wait for the consumed
// buffer leaves the next step's loads (and the 3 b-frag loads) in flight:
// one full step of compute overlaps every HBM latency. Register budget
// ~100 VGPR -> ~5 waves/SIMD (20 waves/CU). B-fragments are 16B loads from
// the padded bf16 codebook (49KB, L2-hot). No barriers in the K-loop.
#define LOADX(buf, c)                                   \
  {                                                     \
    buf[0] = *(const float4*)(xr0 + (c));               \
    buf[1] = *(const float4*)(xr0 + (c) + 4);           \
    buf[2] = *(const float4*)(xr1 + (c));               \
    buf[3] = *(const float4*)(xr1 + (c) + 4);           \
  }

#define COMPUTE(buf, c)                                                        \
  {                                                                            \
    bf16x8 b0 = *(const bf16x8*)(bp + (c));                                    \
    bf16x8 b1 = *(const bf16x8*)(bp + 16 * 512 + (c));                         \
    bf16x8 b2 = *(const bf16x8*)(bp + 32 * 512 + (c));                         \
    float4 p0 = buf[0], p1 = buf[1], q0 = buf[2], q1 = buf[3];                 \
    ss = fmaf(p0.x, p0.x, fmaf(p0.y, p0.y, fmaf(p0.z, p0.z, fmaf(p0.w, p0.w, ss)))); \
    ss = fmaf(p1.x, p1.x, fmaf(p1.y, p1.y, fmaf(p1.z, p1.z, fmaf(p1.w, p1.w, ss)))); \
    ss = fmaf(q0.x, q0.x, fmaf(q0.y, q0.y, fmaf(q0.z, q0.z, fmaf(q0.w, q0.w, ss)))); \
    ss = fmaf(q1.x, q1.x, fmaf(q1.y, q1.y, fmaf(q1.z, q1.z, fmaf(q1.w, q1.w, ss)))); \
    bf16x8 a0, a1;                                                             \
    a0[0] = (short)f2bf(p0.x); a0[1] = (short)f2bf(p0.y);                      \
    a0[2] = (short)f2bf(p0.z); a0[3] = (short)f2bf(p0.w);                      \
    a0[4] = (short)f2bf(p1.x); a0[5] = (short)f2bf(p1.y);                      \
    a0[6] = (short)f2bf(p1.z); a0[7] = (short)f2bf(p1.w);                      \
    a1[0] = (short)f2bf(q0.x); a1[1] = (short)f2bf(q0.y);                      \
    a1[2] = (short)f2bf(q0.z); a1[3] = (short)f2bf(q0.w);                      \
    a1[4] = (short)f2bf(q1.x); a1[5] = (short)f2bf(q1.y);                      \
    a1[6] = (short)f2bf(q1.z); a1[7] = (short)f2bf(q1.w);                      \
    acc[0][0] = __builtin_amdgcn_mfma_f32_16x16x32_bf16(a0, b0, acc[0][0], 0, 0, 0); \
    acc[0][1] = __builtin_amdgcn_mfma_f32_16x16x32_bf16(a0, b1, acc[0][1], 0, 0, 0); \
    acc[0][2] = __builtin_amdgcn_mfma_f32_16x16x32_bf16(a0, b2, acc[0][2], 0, 0, 0); \
    acc[1][0] = __builtin_amdgcn_mfma_f32_16x16x32_bf16(a1, b0, acc[1][0], 0, 0, 0); \
    acc[1][1] = __builtin_amdgcn_mfma_f32_16x16x32_bf16(a1, b1, acc[1][1], 0, 0, 0); \
    acc[1][2] = __builtin_amdgcn_mfma_f32_16x16x32_bf16(a1, b2, acc[1][2], 0, 0, 0); \
  }

__global__ __launch_bounds__(256, 4) void vq_assign(
    const float* __restrict__ x, const unsigned short* __restrict__ embb,
    const float* __restrict__ sq, int* __restrict__ idxp,
    float* __restrict__ counts, float* __restrict__ sumsq) {
  __shared__ float sq_s[KC];
  __shared__ float lcnt[KC];
  __shared__ float lss[4];
  int t = threadIdx.x;
  long row0 = (long)blockIdx.x * 128;
  if (t < KC) { sq_s[t] = sq[t]; lcnt[t] = 0.f; }

  int w = t >> 6, L = t & 63;
  int lm = L & 15, kq = L >> 4;

  const float* xr0 = x + (row0 + w * 32 + 0 * 16 + lm) * (long)D + kq * 8;
  const float* xr1 = x + (row0 + w * 32 + 1 * 16 + lm) * (long)D + kq * 8;
  const unsigned short* bp = embb + lm * 512 + kq * 8;

  float ss = 0.f;
  f32x4 acc[2][3];
  #pragma unroll
  for (int m = 0; m < 2; m++)
    #pragma unroll
    for (int n = 0; n < 3; n++) acc[m][n] = (f32x4){0.f, 0.f, 0.f, 0.f};

  float4 bufA[4], bufB[4];
  LOADX(bufA, 0);
  #pragma unroll 1
  for (int it = 0; it < 7; it++) {  // steps 0..13, pipelined in pairs
    int c0 = it * 64;
    LOADX(bufB, c0 + 32);
    COMPUTE(bufA, c0);
    LOADX(bufA, c0 + 64);
    COMPUTE(bufB, c0 + 32);
  }
  // step 14 (c=448) computes from bufA; step 15 (c=480) is the predicated
  // tail (D=492: kq0 loads both float4s, kq1 only the first, kq2/3 none).
  {
    int cl = 480 + kq * 8;
    bool in0 = cl < D, in1 = cl + 4 < D;
    float4 z = make_float4(0.f, 0.f, 0.f, 0.f);
    bufB[0] = in0 ? *(const float4*)(xr0 + 480) : z;
    bufB[1] = in1 ? *(const float4*)(xr0 + 484) : z;
    bufB[2] = in0 ? *(const float4*)(xr1 + 480) : z;
    bufB[3] = in1 ? *(const float4*)(xr1 + 484) : z;
  }
  COMPUTE(bufA, 448);
  COMPUTE(bufB, 480);

  __syncthreads();  // lcnt zeroed + sq_s visible before epilogue

  // ---- epilogue: per-row argmin of sq[k] - 2*dot (||x||^2 dropped)
  #pragma unroll
  for (int m = 0; m < 2; m++) {
    #pragma unroll
    for (int reg = 0; reg < 4; reg++) {
      float best = 3.4e38f; int bi = 0;
      #pragma unroll
      for (int n = 0; n < 3; n++) {
        int col = n * 16 + lm;
        if (col < KC) {
          float v = sq_s[col] - 2.f * acc[m][n][reg];
          if (v < best || (v == best && col < bi)) { best = v; bi = col; }
        }
      }
      #pragma unroll
      for (int off = 1; off < 16; off <<= 1) {
        float ov = __shfl_xor(best, off, 64);
        int oi = __shfl_xor(bi, off, 64);
        if (ov < best || (ov == best && oi < bi)) { best = ov; bi = oi; }
      }
      if (lm == 0) {
        int r = w * 32 + m * 16 + kq * 4 + reg;
        idxp[row0 + r] = bi;
        atomicAdd(&lcnt[bi], 1.f);
      }
    }
  }
  // ---- sumsq + counts flush
  #pragma unroll
  for (int off = 32; off; off >>= 1) ss += __shfl_down(ss, off, 64);
  if (L == 0) lss[w] = ss;
  __syncthreads();
  if (t == 0) atomicAdd(sumsq, lss[0] + lss[1] + lss[2] + lss[3]);
  if (t < KC) atomicAdd(&counts[t], lcnt[t]);
}

// ---------------------------------------------------------------- K2: dw segment-sum
// Round-3: 512 rows/block (grid 512) but 256 threads (4 waves, 2x TLP).
// Counting-sort rows by code into packed order[] (r | k<<9); the sorted
// list is split at the code-20 boundary (base[20]) into two independent
// halves, each streamed by a 2-wave half-block (123 active col-threads,
// float4 each). Codes never straddle halves, so the flush/atomic count is
// unchanged vs the 128-thread version while memory parallelism doubles.
__global__ __launch_bounds__(256) void vq_dw(
    const float* __restrict__ x, const int* __restrict__ idxp,
    float* __restrict__ dwp) {
  __shared__ int cnt[KC], base[KC], pos[KC];
  __shared__ unsigned short order[512];
  __shared__ int splitS;
  int t = threadIdx.x;
  long row0 = (long)blockIdx.x * 512;
  if (t < KC) cnt[t] = 0;
  __syncthreads();
  int myk0 = idxp[row0 + t];
  int myk1 = idxp[row0 + t + 256];
  atomicAdd(&cnt[myk0], 1);
  atomicAdd(&cnt[myk1], 1);
  __syncthreads();
  if (t == 0) {
    int s = 0;
    for (int k = 0; k < KC; k++) { base[k] = s; pos[k] = s; s += cnt[k]; }
    splitS = base[KC / 2];
  }
  __syncthreads();
  {
    int p = atomicAdd(&pos[myk0], 1);
    order[p] = (unsigned short)(t | (myk0 << 9));
  }
  {
    int p = atomicAdd(&pos[myk1], 1);
    order[p] = (unsigned short)((t + 256) | (myk1 << 9));
  }
  __syncthreads();

  int h = t >> 7, tt = t & 127;
  int lo = h ? splitS : 0;
  int hi = h ? 512 : splitS;
  int c = 4 * tt;
  bool act = c < D;  // 123 of 128 threads per half carry columns
  float* dst = dwp + (long)(blockIdx.x & (PSPREAD - 1)) * (KC * D);
  float4 a = make_float4(0.f, 0.f, 0.f, 0.f);
  int kcur = -1;
  float4 z = make_float4(0.f, 0.f, 0.f, 0.f);

  int nb = (hi - lo) >> 3;  // full 8-batches
  int pk[8], pk2[8];
  float4 v[8], v2[8];
  if (nb > 0) {
    #pragma unroll
    for (int u = 0; u < 8; u++) pk[u] = order[lo + u];
    #pragma unroll
    for (int u = 0; u < 8; u++)
      v[u] = act ? *(const float4*)&x[(row0 + (pk[u] & 511)) * D + c] : z;
    for (int bi = 0; bi < nb; bi++) {
      if (bi + 1 < nb) {
        int j = lo + (bi + 1) * 8;
        #pragma unroll
        for (int u = 0; u < 8; u++) pk2[u] = order[j + u];
        #pragma unroll
        for (int u = 0; u < 8; u++)
          v2[u] = act ? *(const float4*)&x[(row0 + (pk2[u] & 511)) * D + c] : z;
      }
      #pragma unroll
      for (int u = 0; u < 8; u++) {
        int k = pk[u] >> 9;           // wave-uniform (order[] shared per half)
        if (k != kcur) {              // uniform branch, ~40 flushes per block
          if (kcur >= 0 && act) {
            atomicAdd(&dst[kcur * D + c], a.x);
            atomicAdd(&dst[kcur * D + c + 1], a.y);
            atomicAdd(&dst[kcur * D + c + 2], a.z);
            atomicAdd(&dst[kcur * D + c + 3], a.w);
          }
          a = v[u]; kcur = k;
        } else {
          a.x += v[u].x; a.y += v[u].y; a.z += v[u].z; a.w += v[u].w;
        }
      }
      #pragma unroll
      for (int u = 0; u < 8; u++) { pk[u] = pk2[u]; v[u] = v2[u]; }
    }
  }
  // tail (< 8 entries)
  for (int j = lo + nb * 8; j < hi; j++) {
    int e = order[j];
    int k = e >> 9;
    float4 vv = act ? *(const float4*)&x[(row0 + (e & 511)) * D + c] : z;
    if (k != kcur) {
      if (kcur >= 0 && act) {
        atomicAdd(&dst[kcur * D + c], a.x);
        atomicAdd(&dst[kcur * D + c + 1], a.y);
        atomicAdd(&dst[kcur * D + c + 2], a.z);
        atomicAdd(&dst[kcur * D + c + 3], a.w);
      }
      a = vv; kcur = k;
    } else {
      a.x += vv.x; a.y += vv.y; a.z += vv.z; a.w += vv.w;
    }
  }
  if (kcur >= 0 && act) {
    atomicAdd(&dst[kcur * D + c], a.x);
    atomicAdd(&dst[kcur * D + c + 1], a.y);
    atomicAdd(&dst[kcur * D + c + 2], a.z);
    atomicAdd(&dst[kcur * D + c + 3], a.w);
  }
}

// ---------------------------------------------------------------- K3a: reduce 64 partials -> dw
__global__ __launch_bounds__(256) void vq_reduce(
    const float* __restrict__ dwp, float* __restrict__ dw) {
  int i = blockIdx.x * 256 + threadIdx.x;
  if (i >= KC * D) return;
  float s = 0.f;
  #pragma unroll 8
  for (int cpy = 0; cpy < PSPREAD; cpy++) s += dwp[cpy * (KC * D) + i];
  dw[i] = s;
}

// ---------------------------------------------------------------- K3b: EMA + closed-form loss
// loss*N*D = sumsq - 2*sum_k E_k.dw_k + sum_k counts_k*||E_k||^2
__global__ __launch_bounds__(256) void vq_final(
    const float* __restrict__ ema_w, const float* __restrict__ ema_cs,
    const float* __restrict__ counts, const float* __restrict__ dw,
    const float* __restrict__ sumsq, float* __restrict__ out, long NDl) {
  __shared__ float lcs[KC], lcnt[KC];
  __shared__ float r1[4], r2[4];
  int t = threadIdx.x;
  if (t < KC) {
    float c = counts[t];
    lcnt[t] = c;
    lcs[t] = ema_cs[t] * DECAY + (1.f - DECAY) * c;
  }
  __syncthreads();
  if (t == 0) {
    float n = 0.f;
    for (int k = 0; k < KC; k++) n += lcs[k];
    for (int k = 0; k < KC; k++) lcs[k] = (lcs[k] + EPS) / (n + KC * EPS) * n;
  }
  __syncthreads();
  float t1 = 0.f, t2 = 0.f;
  for (int i = t; i < KC * D; i += 256) {
    float dwv = dw[i];
    int k = i / D;
    float E = (DECAY * ema_w[i] + (1.f - DECAY) * dwv) / lcs[k];
    t1 = fmaf(lcnt[k] * E, E, t1);
    t2 = fmaf(E, dwv, t2);
  }
  #pragma unroll
  for (int off = 32; off; off >>= 1) {
    t1 += __shfl_down(t1, off, 64);
    t2 += __shfl_down(t2, off, 64);
  }
  int lane = t & 63, w = t >> 6;
  if (lane == 0) { r1[w] = t1; r2[w] = t2; }
  __syncthreads();
  if (t == 0) {
    double T1 = (double)r1[0] + r1[1] + r1[2] + r1[3];
    double T2 = (double)r2[0] + r2[1] + r2[2] + r2[3];
    double L = ((double)sumsq[0] - 2.0 * T2 + T1) / (double)NDl;
    out[0] = (float)L;
  }
}

// ---------------------------------------------------------------- launch
extern "C" void kernel_launch(void* const* d_in, const int* in_sizes, int n_in,
                              void* d_out, int out_size, void* d_ws, size_t ws_size,
                              hipStream_t stream) {
  const float* x = (const float*)d_in[0];
  const float* emb = (const float*)d_in[1];
  const float* ema_w = (const float*)d_in[2];
  const float* ema_cs = (const float*)d_in[3];
  float* out = (float*)d_out;
  long NDl = (long)in_sizes[0];
  int N = (int)(NDl / D);  // 262144

  char* ws = (char*)d_ws;
  float* sq = (float*)ws;                         // 40 f
  float* counts = (float*)(ws + 256);             // 40 f
  float* sumsq = (float*)(ws + 512);              // 1 f
  float* dw = (float*)(ws + 1024);                // KC*D f (reduced)
  size_t part_off = 1024 + (size_t)KC * D * 4;
  part_off = (part_off + 255) & ~(size_t)255;
  float* dwp = (float*)(ws + part_off);           // PSPREAD * KC*D f
  size_t idx_off = part_off + (size_t)PSPREAD * KC * D * 4;
  int* idxp = (int*)(ws + idx_off);               // N ints
  size_t embb_off = idx_off + (size_t)N * 4;
  unsigned short* embb = (unsigned short*)(ws + embb_off);  // 48*512 bf16

  hipMemsetAsync(ws + 256, 0, 768, stream);
  hipMemsetAsync(ws + part_off, 0, (size_t)PSPREAD * KC * D * 4, stream);

  vq_prep<<<48, 64, 0, stream>>>(emb, sq, embb);
  vq_assign<<<N / 128, 256, 0, stream>>>(x, embb, sq, idxp, counts, sumsq);
  vq_dw<<<N / 512, 256, 0, stream>>>(x, idxp, dwp);
  vq_reduce<<<(KC * D + 255) / 256, 256, 0, stream>>>(dwp, dw);
  vq_final<<<1, 256, 0, stream>>>(ema_w, ema_cs, counts, dw, sumsq, out, NDl);
}